// Round 5
// baseline (196.589 us; speedup 1.0000x reference)
//
#include <hip/hip_runtime.h>
#include <hip/hip_cooperative_groups.h>
#include <math.h>

namespace cg = cooperative_groups;

#define B    64
#define L1   199
#define L    200
#define NC   1000
#define D    64
#define M    50
#define SEG  4      // time segments (one block per (b,seg))
#define TS   50     // t per segment
#define WV   5      // waves per block
#define MPW  10     // m rows per wave (WV*MPW = M)
#define BLK  320
#define GRID 256    // B*SEG

// Single cooperative kernel: tables -> stage -> scanA -> sync -> prefix+scan
// -> in-LDS reduce -> phase3 -> out. One launch, no rp round-trip.
__global__ __launch_bounds__(BLK, 1) void fused(
    const int* __restrict__ cseqs, const int* __restrict__ rseqs,
    const int* __restrict__ shft_cseqs, const int* __restrict__ shft_rseqs,
    const float* __restrict__ kemb, const float* __restrict__ vemb,
    const float* __restrict__ Mk, const float* __restrict__ Mv0,
    const float* __restrict__ We, const float* __restrict__ be,
    const float* __restrict__ Wa, const float* __restrict__ ba,
    const float* __restrict__ Wf, const float* __restrict__ bf,
    const float* __restrict__ Wp, const float* __restrict__ bp,
    float* __restrict__ out,
    float* __restrict__ wtab, float* __restrict__ etab,
    float* __restrict__ atab, float* __restrict__ ktab,
    float* __restrict__ abuf, float* __restrict__ bbuf)
{
    __shared__ __align__(16) float s_part[WV][TS][D];   // 64.0 KB (also phase-0 scratch)
    __shared__ __align__(16) float s_ea[2][TS][D];      // 25.6 KB (e,a rows; later read-rows)
    __shared__ __align__(16) float s_w[TS][M];          // 10.0 KB
    __shared__ int s_q[TS];
    __shared__ int s_x[TS];

    const int tid  = threadIdx.x;
    const int lane = tid & 63;
    const int wv   = tid >> 6;
    const int blk  = blockIdx.x;
    cg::grid_group grid = cg::this_grid();

    // ================= phase 0: id-indexed tables =================
    // tasks 0..1499, 4 rows each; 1280 waves loop over them.
    {
        float* lrow = &s_part[wv][0][0];   // per-wave scratch (256 floats)
        for (int task = blk * WV + wv; task < 1500; task += GRID * WV) {
            if (task < 250) {
                // wtab[q][m] = softmax(kemb[q] @ Mk^T)
                const int r0 = task * 4;
                #pragma unroll
                for (int i = 0; i < 4; ++i)
                    lrow[i * D + lane] = kemb[(size_t)(r0 + i) * D + lane];
                float Mk_r[D];
                {
                    const int mrow = (lane < M) ? lane : (M - 1);
                    #pragma unroll
                    for (int d = 0; d < D; d += 4) {
                        const float4 t4 = *(const float4*)(Mk + mrow * D + d);
                        Mk_r[d]=t4.x; Mk_r[d+1]=t4.y; Mk_r[d+2]=t4.z; Mk_r[d+3]=t4.w;
                    }
                }
                #pragma unroll
                for (int i = 0; i < 4; ++i) {
                    float c0 = 0.f, c1 = 0.f;
                    #pragma unroll
                    for (int d = 0; d < D; d += 4) {
                        const float4 kb = *(const float4*)&lrow[i * D + d];
                        c0 = fmaf(Mk_r[d],     kb.x, c0);
                        c1 = fmaf(Mk_r[d + 1], kb.y, c1);
                        c0 = fmaf(Mk_r[d + 2], kb.z, c0);
                        c1 = fmaf(Mk_r[d + 3], kb.w, c1);
                    }
                    const float logit = (lane < M) ? (c0 + c1) : -INFINITY;
                    float mx = logit;
                    #pragma unroll
                    for (int off = 32; off; off >>= 1) mx = fmaxf(mx, __shfl_xor(mx, off, 64));
                    const float ex = expf(logit - mx);
                    float sm = ex;
                    #pragma unroll
                    for (int off = 32; off; off >>= 1) sm += __shfl_xor(sm, off, 64);
                    if (lane < M) wtab[(size_t)(r0 + i) * M + lane] = ex / sm;
                }
            } else if (task < 1250) {
                // etab / atab
                const bool is_e = (task < 750);
                const int  r0   = (is_e ? (task - 250) : (task - 750)) * 4;
                #pragma unroll
                for (int i = 0; i < 4; ++i)
                    lrow[i * D + lane] = vemb[(size_t)(r0 + i) * D + lane];
                const float* __restrict__ W   = is_e ? We : Wa;
                float*       __restrict__ dst = is_e ? etab : atab;
                float Wc[D];
                #pragma unroll
                for (int din = 0; din < D; ++din) Wc[din] = W[din * D + lane];
                const float br = is_e ? be[lane] : ba[lane];
                #pragma unroll
                for (int i = 0; i < 4; ++i) {
                    float c0 = 0.f, c1 = 0.f;
                    #pragma unroll
                    for (int d = 0; d < D; d += 4) {
                        const float4 vb = *(const float4*)&lrow[i * D + d];
                        c0 = fmaf(Wc[d],     vb.x, c0);
                        c1 = fmaf(Wc[d + 1], vb.y, c1);
                        c0 = fmaf(Wc[d + 2], vb.z, c0);
                        c1 = fmaf(Wc[d + 3], vb.w, c1);
                    }
                    const float acc = c0 + c1;
                    const float r = is_e ? (1.f / (1.f + expf(-(acc + br))))
                                         : tanhf(acc + br);
                    dst[(size_t)(r0 + i) * D + lane] = r;
                }
            } else {
                // ktab[q][d] = kemb[q] @ Wf[D:2D]
                const int r0 = (task - 1250) * 4;
                #pragma unroll
                for (int i = 0; i < 4; ++i)
                    lrow[i * D + lane] = kemb[(size_t)(r0 + i) * D + lane];
                float Wc[D];
                #pragma unroll
                for (int i = 0; i < D; ++i) Wc[i] = Wf[(size_t)(D + i) * D + lane];
                #pragma unroll
                for (int i = 0; i < 4; ++i) {
                    float f1 = 0.f;
                    #pragma unroll
                    for (int d = 0; d < D; d += 4) {
                        const float4 kb = *(const float4*)&lrow[i * D + d];
                        f1 = fmaf(Wc[d],     kb.x, f1);
                        f1 = fmaf(Wc[d + 1], kb.y, f1);
                        f1 = fmaf(Wc[d + 2], kb.z, f1);
                        f1 = fmaf(Wc[d + 3], kb.w, f1);
                    }
                    ktab[(size_t)(r0 + i) * D + lane] = f1;
                }
            }
        }
    }
    grid.sync();

    // ================= stage this block's (b,seg) slice into LDS =================
    const int b  = blk >> 2;
    const int s  = blk & 3;
    const int t0 = s * TS;
    const int m0 = wv * MPW;

    if (wv == 0 && lane < TS) {
        const int t = t0 + lane;
        int q, r;
        if (t == 0) { q = cseqs[b * L1];              r = rseqs[b * L1]; }
        else        { q = shft_cseqs[b * L1 + t - 1]; r = shft_rseqs[b * L1 + t - 1]; }
        s_q[lane] = q;
        s_x[lane] = q + NC * r;
    }
    __syncthreads();

    // e/a rows: wave wv stages t in [wv*10, wv*10+10)
    #pragma unroll
    for (int j = 0; j < MPW; ++j) {
        const int t = wv * MPW + j;
        const int x = s_x[t];
        s_ea[0][t][lane] = etab[(size_t)x * D + lane];
        s_ea[1][t][lane] = atab[(size_t)x * D + lane];
    }
    // w columns: wave wv stages m in [m0, m0+10), lane = t
    if (lane < TS) {
        const int qq = s_q[lane];
        const float* __restrict__ wp_ = wtab + (size_t)qq * M + m0;
        #pragma unroll
        for (int j = 0; j < MPW; ++j) s_w[lane][m0 + j] = wp_[j];
    }
    __syncthreads();

    // ================= scanA: segment affine composition (s < 3) =================
    if (s < 3) {
        float A[MPW], Bv[MPW];
        #pragma unroll
        for (int j = 0; j < MPW; ++j) { A[j] = 1.f; Bv[j] = 0.f; }
        for (int t = 0; t < TS; ++t) {
            const float ed = s_ea[0][t][lane];
            const float ad = s_ea[1][t][lane];
            #pragma unroll
            for (int j = 0; j < MPW; ++j) {
                const float wm = s_w[t][m0 + j];
                const float we = wm * ed;
                A[j]  = fmaf(A[j],  -we, A[j]);
                Bv[j] = fmaf(Bv[j], -we, fmaf(wm, ad, Bv[j]));
            }
        }
        #pragma unroll
        for (int j = 0; j < MPW; ++j) {
            abuf[((size_t)(b * 3 + s) * M + m0 + j) * D + lane] = A[j];
            bbuf[((size_t)(b * 3 + s) * M + m0 + j) * D + lane] = Bv[j];
        }
    }
    grid.sync();

    // ================= prefix-compose + scan (LDS staging still valid) =================
    float Mv[MPW];
    #pragma unroll
    for (int j = 0; j < MPW; ++j) Mv[j] = Mv0[(m0 + j) * D + lane];
    for (int ss = 0; ss < s; ++ss) {
        #pragma unroll
        for (int j = 0; j < MPW; ++j) {
            const float a_ = abuf[((size_t)(b * 3 + ss) * M + m0 + j) * D + lane];
            const float b_ = bbuf[((size_t)(b * 3 + ss) * M + m0 + j) * D + lane];
            Mv[j] = fmaf(a_, Mv[j], b_);
        }
    }

    for (int t = 0; t < TS; ++t) {
        const float ed = s_ea[0][t][lane];
        const float ad = s_ea[1][t][lane];
        float r0a = 0.f, r1a = 0.f, r0b = 0.f, r1b = 0.f;
        // old chunk 2*wv: j=0..4 (even/odd as before)
        #pragma unroll
        for (int j = 0; j < 5; ++j) {
            const float wm = s_w[t][m0 + j];
            if (j & 1) r1a = fmaf(wm, Mv[j], r1a);
            else       r0a = fmaf(wm, Mv[j], r0a);
            const float we = wm * ed;
            Mv[j] = fmaf(Mv[j], -we, fmaf(wm, ad, Mv[j]));
        }
        // old chunk 2*wv+1: j=5..9 (local parity)
        #pragma unroll
        for (int j = 5; j < 10; ++j) {
            const float wm = s_w[t][m0 + j];
            if ((j - 5) & 1) r1b = fmaf(wm, Mv[j], r1b);
            else             r0b = fmaf(wm, Mv[j], r0b);
            const float we = wm * ed;
            Mv[j] = fmaf(Mv[j], -we, fmaf(wm, ad, Mv[j]));
        }
        s_part[wv][t][lane] = (r0a + r1a) + (r0b + r1b);
    }
    __syncthreads();

    // ================= reduce partials + phase3, write out =================
    {
        float Wf_c[D];
        #pragma unroll
        for (int i = 0; i < D; ++i) Wf_c[i] = Wf[(size_t)i * D + lane];
        const float bf_r = bf[lane];
        const float wp_r = Wp[lane];
        const float bp_r = bp[0];

        #pragma unroll
        for (int j = 0; j < MPW; ++j) {
            const int t = wv * MPW + j;   // this wave owns t in [wv*10, wv*10+10)
            const float rd = (((s_part[0][t][lane] + s_part[1][t][lane])
                              + s_part[2][t][lane]) + s_part[3][t][lane])
                              + s_part[4][t][lane];
            const float kt = ktab[(size_t)s_q[t] * D + lane];
            s_ea[0][t][lane] = rd;        // wave-local row; DS in-order within wave
            float f0 = 0.f;
            #pragma unroll
            for (int i = 0; i < D; i += 4) {
                const float4 rb = *(const float4*)&s_ea[0][t][i];   // uniform broadcast
                f0 = fmaf(Wf_c[i],     rb.x, f0);
                f0 = fmaf(Wf_c[i + 1], rb.y, f0);
                f0 = fmaf(Wf_c[i + 2], rb.z, f0);
                f0 = fmaf(Wf_c[i + 3], rb.w, f0);
            }
            const float f = tanhf(f0 + kt + bf_r);
            float c = f * wp_r;
            #pragma unroll
            for (int off = 32; off; off >>= 1) c += __shfl_xor(c, off, 64);
            if (lane == 0) out[b * L + t0 + t] = 1.f / (1.f + expf(-(c + bp_r)));
        }
    }
}

extern "C" void kernel_launch(void* const* d_in, const int* in_sizes, int n_in,
                              void* d_out, int out_size, void* d_ws, size_t ws_size,
                              hipStream_t stream) {
    const int*   cseqs      = (const int*)d_in[0];
    const int*   rseqs      = (const int*)d_in[1];
    const int*   shft_cseqs = (const int*)d_in[2];
    const int*   shft_rseqs = (const int*)d_in[3];
    const float* kemb = (const float*)d_in[4];
    const float* vemb = (const float*)d_in[5];
    const float* Mk   = (const float*)d_in[6];
    const float* Mv0  = (const float*)d_in[7];
    const float* Wf   = (const float*)d_in[8];
    const float* bf   = (const float*)d_in[9];
    const float* We   = (const float*)d_in[10];
    const float* be   = (const float*)d_in[11];
    const float* Wa   = (const float*)d_in[12];
    const float* ba   = (const float*)d_in[13];
    const float* Wp   = (const float*)d_in[14];
    const float* bp   = (const float*)d_in[15];
    float* out = (float*)d_out;

    float* ws   = (float*)d_ws;
    float* wtab = ws;                          // 1000*50  =  50000 floats
    float* etab = wtab + (size_t)NC * M;       // 2000*64  = 128000
    float* atab = etab + (size_t)2 * NC * D;   // 2000*64  = 128000
    float* ktab = atab + (size_t)2 * NC * D;   // 1000*64  =  64000
    float* abuf = ktab + (size_t)NC * D;       // 64*3*50*64 = 614400
    float* bbuf = abuf + (size_t)B * 3 * M * D;// 614400   (~6.4 MB total)

    void* args[] = {
        (void*)&cseqs, (void*)&rseqs, (void*)&shft_cseqs, (void*)&shft_rseqs,
        (void*)&kemb, (void*)&vemb, (void*)&Mk, (void*)&Mv0,
        (void*)&We, (void*)&be, (void*)&Wa, (void*)&ba,
        (void*)&Wf, (void*)&bf, (void*)&Wp, (void*)&bp,
        (void*)&out, (void*)&wtab, (void*)&etab, (void*)&atab,
        (void*)&ktab, (void*)&abuf, (void*)&bbuf };

    hipLaunchCooperativeKernel((void*)fused, dim3(GRID), dim3(BLK), args, 0, stream);
}

// Round 6
// 124.351 us; speedup vs baseline: 1.5809x; 1.5809x over previous
//
#include <hip/hip_runtime.h>
#include <math.h>

#define B    64
#define L1   199
#define L    200
#define NC   1000
#define D    64
#define M    50
#define SEG  4      // time segments (one block per (b,seg))
#define TS   50     // t per segment
#define WV   5      // waves per block
#define MPW  10     // m rows per wave (WV*MPW = M)
#define BLK  320

// ---------------- K1: id-indexed tables (verbatim from the round-3 passing kernel).
//   [0,250):     wtab[q][m]  = softmax(kemb[q] @ Mk^T)
//   [250,750):   etab[x][d]  = sigmoid(vemb[x] @ We + be)
//   [750,1250):  atab[x][d]  = tanh   (vemb[x] @ Wa + ba)
//   [1250,1500): ktab[q][d]  = kemb[q] @ Wf[D:2D]
__global__ __launch_bounds__(64) void phase0(
    const float* __restrict__ kemb, const float* __restrict__ vemb,
    const float* __restrict__ Mk,
    const float* __restrict__ We, const float* __restrict__ be,
    const float* __restrict__ Wa, const float* __restrict__ ba,
    const float* __restrict__ Wf,
    float* __restrict__ wtab, float* __restrict__ etab,
    float* __restrict__ atab, float* __restrict__ ktab)
{
    __shared__ __align__(16) float lrow[4 * D];
    const int lane = threadIdx.x;
    const int bid  = blockIdx.x;

    if (bid < 250) {
        const int r0 = bid * 4;
        #pragma unroll
        for (int i = 0; i < 4; ++i)
            lrow[i * D + lane] = kemb[(size_t)(r0 + i) * D + lane];
        __syncthreads();

        float Mk_r[D];
        {
            const int mrow = (lane < M) ? lane : (M - 1);
            #pragma unroll
            for (int d = 0; d < D; d += 4) {
                const float4 t4 = *(const float4*)(Mk + mrow * D + d);
                Mk_r[d] = t4.x; Mk_r[d+1] = t4.y; Mk_r[d+2] = t4.z; Mk_r[d+3] = t4.w;
            }
        }
        #pragma unroll
        for (int i = 0; i < 4; ++i) {
            float c0 = 0.f, c1 = 0.f;
            #pragma unroll
            for (int d = 0; d < D; d += 4) {
                const float4 kb = *(const float4*)&lrow[i * D + d];
                c0 = fmaf(Mk_r[d],     kb.x, c0);
                c1 = fmaf(Mk_r[d + 1], kb.y, c1);
                c0 = fmaf(Mk_r[d + 2], kb.z, c0);
                c1 = fmaf(Mk_r[d + 3], kb.w, c1);
            }
            const float logit = (lane < M) ? (c0 + c1) : -INFINITY;
            float mx = logit;
            #pragma unroll
            for (int off = 32; off; off >>= 1) mx = fmaxf(mx, __shfl_xor(mx, off, 64));
            const float ex = expf(logit - mx);
            float sm = ex;
            #pragma unroll
            for (int off = 32; off; off >>= 1) sm += __shfl_xor(sm, off, 64);
            if (lane < M) wtab[(size_t)(r0 + i) * M + lane] = ex / sm;
        }
    } else if (bid < 1250) {
        const bool is_e = (bid < 750);
        const int  r0   = (is_e ? (bid - 250) : (bid - 750)) * 4;
        #pragma unroll
        for (int i = 0; i < 4; ++i)
            lrow[i * D + lane] = vemb[(size_t)(r0 + i) * D + lane];
        __syncthreads();

        const float* __restrict__ W   = is_e ? We : Wa;
        float*       __restrict__ dst = is_e ? etab : atab;
        float Wc[D];
        #pragma unroll
        for (int din = 0; din < D; ++din) Wc[din] = W[din * D + lane];
        const float br = is_e ? be[lane] : ba[lane];

        #pragma unroll
        for (int i = 0; i < 4; ++i) {
            float c0 = 0.f, c1 = 0.f;
            #pragma unroll
            for (int d = 0; d < D; d += 4) {
                const float4 vb = *(const float4*)&lrow[i * D + d];
                c0 = fmaf(Wc[d],     vb.x, c0);
                c1 = fmaf(Wc[d + 1], vb.y, c1);
                c0 = fmaf(Wc[d + 2], vb.z, c0);
                c1 = fmaf(Wc[d + 3], vb.w, c1);
            }
            const float acc = c0 + c1;
            const float r = is_e ? (1.f / (1.f + expf(-(acc + br))))
                                 : tanhf(acc + br);
            dst[(size_t)(r0 + i) * D + lane] = r;
        }
    } else {
        const int r0 = (bid - 1250) * 4;
        #pragma unroll
        for (int i = 0; i < 4; ++i)
            lrow[i * D + lane] = kemb[(size_t)(r0 + i) * D + lane];
        __syncthreads();

        float Wc[D];
        #pragma unroll
        for (int i = 0; i < D; ++i) Wc[i] = Wf[(size_t)(D + i) * D + lane];

        #pragma unroll
        for (int i = 0; i < 4; ++i) {
            float f1 = 0.f;
            #pragma unroll
            for (int d = 0; d < D; d += 4) {
                const float4 kb = *(const float4*)&lrow[i * D + d];
                f1 = fmaf(Wc[d],     kb.x, f1);
                f1 = fmaf(Wc[d + 1], kb.y, f1);
                f1 = fmaf(Wc[d + 2], kb.z, f1);
                f1 = fmaf(Wc[d + 3], kb.w, f1);
            }
            ktab[(size_t)(r0 + i) * D + lane] = f1;
        }
    }
}

// ---------------- K2: per (b,seg) block. Replay the recurrence over preceding
// segments (no cross-block data), scan own segment with read-emission,
// reduce wave-partials in LDS, apply phase3, write out. No grid sync.
__global__ __launch_bounds__(BLK, 1) void scan3(
    const int* __restrict__ cseqs, const int* __restrict__ rseqs,
    const int* __restrict__ shft_cseqs, const int* __restrict__ shft_rseqs,
    const float* __restrict__ Mv0,
    const float* __restrict__ wtab, const float* __restrict__ etab,
    const float* __restrict__ atab, const float* __restrict__ ktab,
    const float* __restrict__ Wf, const float* __restrict__ bf,
    const float* __restrict__ Wp, const float* __restrict__ bp,
    float* __restrict__ out)
{
    __shared__ __align__(16) float s_ea[2][TS][D];     // 25.6 KB (e,a rows; later rd rows)
    __shared__ __align__(16) float s_ww[WV][TS][12];   // 12.0 KB (per-wave w slices)
    __shared__ __align__(16) float s_part[WV][TS][D];  // 64.0 KB (read partials)
    __shared__ int s_q[L];
    __shared__ int s_x[L];

    const int tid  = threadIdx.x;
    const int lane = tid & 63;
    const int wv   = tid >> 6;
    const int blk  = blockIdx.x;
    const int b    = blk >> 2;
    const int s    = blk & 3;
    const int m0   = wv * MPW;

    // token ids for the whole sequence (only [0,(s+1)*TS) used)
    if (tid < L) {
        const int t = tid;
        int q, r;
        if (t == 0) { q = cseqs[b * L1];              r = rseqs[b * L1]; }
        else        { q = shft_cseqs[b * L1 + t - 1]; r = shft_rseqs[b * L1 + t - 1]; }
        s_q[t] = q;
        s_x[t] = q + NC * r;
    }
    __syncthreads();

    float Mv[MPW];
    #pragma unroll
    for (int j = 0; j < MPW; ++j) Mv[j] = Mv0[(m0 + j) * D + lane];

    for (int ss = 0; ss <= s; ++ss) {
        const int tb = ss * TS;
        // ---- stage segment ss from the L2-hot tables
        #pragma unroll
        for (int j = 0; j < MPW; ++j) {
            const int t = wv * MPW + j;
            const int x = s_x[tb + t];
            s_ea[0][t][lane] = etab[(size_t)x * D + lane];
            s_ea[1][t][lane] = atab[(size_t)x * D + lane];
        }
        if (lane < TS) {
            const int q = s_q[tb + lane];
            const float* __restrict__ wp_ = wtab + (size_t)q * M + m0;
            #pragma unroll
            for (int j = 0; j < MPW; ++j) s_ww[wv][lane][j] = wp_[j];
        }
        __syncthreads();

        if (ss < s) {
            // ---- replay (no emission): exact recurrence forms
            for (int t = 0; t < TS; ++t) {
                const float ed = s_ea[0][t][lane];
                const float ad = s_ea[1][t][lane];
                float wl[MPW];
                *(float4*)&wl[0] = *(const float4*)&s_ww[wv][t][0];
                *(float4*)&wl[4] = *(const float4*)&s_ww[wv][t][4];
                wl[8] = s_ww[wv][t][8];
                wl[9] = s_ww[wv][t][9];
                #pragma unroll
                for (int j = 0; j < MPW; ++j) {
                    const float wm = wl[j];
                    const float we = wm * ed;
                    Mv[j] = fmaf(Mv[j], -we, fmaf(wm, ad, Mv[j]));
                }
            }
        } else {
            // ---- own segment: scan + read-emission (round-5 verified body)
            for (int t = 0; t < TS; ++t) {
                const float ed = s_ea[0][t][lane];
                const float ad = s_ea[1][t][lane];
                float wl[MPW];
                *(float4*)&wl[0] = *(const float4*)&s_ww[wv][t][0];
                *(float4*)&wl[4] = *(const float4*)&s_ww[wv][t][4];
                wl[8] = s_ww[wv][t][8];
                wl[9] = s_ww[wv][t][9];
                float r0a = 0.f, r1a = 0.f, r0b = 0.f, r1b = 0.f;
                #pragma unroll
                for (int j = 0; j < 5; ++j) {
                    const float wm = wl[j];
                    if (j & 1) r1a = fmaf(wm, Mv[j], r1a);
                    else       r0a = fmaf(wm, Mv[j], r0a);
                    const float we = wm * ed;
                    Mv[j] = fmaf(Mv[j], -we, fmaf(wm, ad, Mv[j]));
                }
                #pragma unroll
                for (int j = 5; j < 10; ++j) {
                    const float wm = wl[j];
                    if ((j - 5) & 1) r1b = fmaf(wm, Mv[j], r1b);
                    else             r0b = fmaf(wm, Mv[j], r0b);
                    const float we = wm * ed;
                    Mv[j] = fmaf(Mv[j], -we, fmaf(wm, ad, Mv[j]));
                }
                s_part[wv][t][lane] = (r0a + r1a) + (r0b + r1b);
            }
        }
        __syncthreads();
    }

    // ---- reduce partials + phase3, write out (round-5 verified forms)
    {
        float Wf_c[D];
        #pragma unroll
        for (int i = 0; i < D; ++i) Wf_c[i] = Wf[(size_t)i * D + lane];
        const float bf_r = bf[lane];
        const float wp_r = Wp[lane];
        const float bp_r = bp[0];
        const int t0 = s * TS;

        #pragma unroll
        for (int j = 0; j < MPW; ++j) {
            const int t = wv * MPW + j;   // this wave owns t in [wv*10, wv*10+10)
            const float rd = (((s_part[0][t][lane] + s_part[1][t][lane])
                              + s_part[2][t][lane]) + s_part[3][t][lane])
                              + s_part[4][t][lane];
            const float kt = ktab[(size_t)s_q[t0 + t] * D + lane];
            s_ea[0][t][lane] = rd;        // wave-local row; DS in-order within wave
            float f0 = 0.f;
            #pragma unroll
            for (int i = 0; i < D; i += 4) {
                const float4 rb = *(const float4*)&s_ea[0][t][i];   // uniform broadcast
                f0 = fmaf(Wf_c[i],     rb.x, f0);
                f0 = fmaf(Wf_c[i + 1], rb.y, f0);
                f0 = fmaf(Wf_c[i + 2], rb.z, f0);
                f0 = fmaf(Wf_c[i + 3], rb.w, f0);
            }
            const float f = tanhf(f0 + kt + bf_r);
            float c = f * wp_r;
            #pragma unroll
            for (int off = 32; off; off >>= 1) c += __shfl_xor(c, off, 64);
            if (lane == 0) out[b * L + t0 + t] = 1.f / (1.f + expf(-(c + bp_r)));
        }
    }
}

extern "C" void kernel_launch(void* const* d_in, const int* in_sizes, int n_in,
                              void* d_out, int out_size, void* d_ws, size_t ws_size,
                              hipStream_t stream) {
    const int*   cseqs      = (const int*)d_in[0];
    const int*   rseqs      = (const int*)d_in[1];
    const int*   shft_cseqs = (const int*)d_in[2];
    const int*   shft_rseqs = (const int*)d_in[3];
    const float* kemb = (const float*)d_in[4];
    const float* vemb = (const float*)d_in[5];
    const float* Mk   = (const float*)d_in[6];
    const float* Mv0  = (const float*)d_in[7];
    const float* Wf   = (const float*)d_in[8];
    const float* bf   = (const float*)d_in[9];
    const float* We   = (const float*)d_in[10];
    const float* be   = (const float*)d_in[11];
    const float* Wa   = (const float*)d_in[12];
    const float* ba   = (const float*)d_in[13];
    const float* Wp   = (const float*)d_in[14];
    const float* bp   = (const float*)d_in[15];
    float* out = (float*)d_out;

    float* ws   = (float*)d_ws;
    float* wtab = ws;                          // 1000*50  =  50000 floats
    float* etab = wtab + (size_t)NC * M;       // 2000*64  = 128000
    float* atab = etab + (size_t)2 * NC * D;   // 2000*64  = 128000
    float* ktab = atab + (size_t)2 * NC * D;   // 1000*64  =  64000  (~1.5 MB total)

    phase0<<<dim3(1500), dim3(64), 0, stream>>>(
        kemb, vemb, Mk, We, be, Wa, ba, Wf, wtab, etab, atab, ktab);
    scan3<<<dim3(B * SEG), dim3(BLK), 0, stream>>>(
        cseqs, rseqs, shft_cseqs, shft_rseqs, Mv0,
        wtab, etab, atab, ktab, Wf, bf, Wp, bp, out);
}